// Round 9
// baseline (8084.488 us; speedup 1.0000x reference)
//
#include <hip/hip_runtime.h>
#include <hip/hip_bf16.h>
#include <hip/hip_fp16.h>

typedef _Float16 f16;
typedef _Float16 h2_t __attribute__((ext_vector_type(2)));
typedef _Float16 h4_t __attribute__((ext_vector_type(4)));
typedef _Float16 h8_t __attribute__((ext_vector_type(8)));
typedef float    f4_t __attribute__((ext_vector_type(4)));

#define B_  64
#define T_  2048
#define BT_ 131072   // B_*T_
#define OG_ELEMS 33554432ull  // BT_*256

// ---------- async global->LDS (16B per lane, wave-uniform LDS base) ----------
__device__ __forceinline__ void gl_lds16(const void* g, void* lds) {
  __builtin_amdgcn_global_load_lds(
      (const __attribute__((address_space(1))) void*)g,
      (__attribute__((address_space(3))) void*)lds, 16, 0, 0);
}

__device__ __forceinline__ float fastrcp(float x)  { return __builtin_amdgcn_rcpf(x); }
__device__ __forceinline__ float fastex2(float x)  { return __builtin_amdgcn_exp2f(x); }

// ---------- m97-style K-loop: 128x128 tile, BK=32, f16 MFMA ----------
__device__ __forceinline__ void kloop128(
    const f16* __restrict__ Ab, int lda,
    const f16* __restrict__ Bb, int ldb,
    int ksteps, f16* As, f16* Bs, f4_t (&acc)[4][4])
{
  const int tid  = threadIdx.x;
  const int wave = tid >> 6, lane = tid & 63;
  const int srow = tid >> 2;
  const int scol = (tid & 3) * 8;
  const int fr   = lane & 15;
  const int kb   = (lane >> 4) * 8;
  const int rA   = (wave >> 1) * 64 + fr;
  const int rB   = (wave & 1) * 64 + fr;

  f16* dA0 = As + wave * 512;
  f16* dA1 = As + 2048 + wave * 512;
  f16* dB0 = Bs + wave * 512;
  f16* dB1 = Bs + 2048 + wave * 512;
  const f16* gA0 = Ab + (size_t)srow * lda + scol;
  const f16* gA1 = Ab + (size_t)(srow + 64) * lda + scol;
  const f16* gB0 = Bb + (size_t)srow * ldb + scol;
  const f16* gB1 = Bb + (size_t)(srow + 64) * ldb + scol;

  for (int kt = 0; kt < ksteps; ++kt) {
    const int ko = kt * 32;
    gl_lds16(gA0 + ko, dA0);
    gl_lds16(gA1 + ko, dA1);
    gl_lds16(gB0 + ko, dB0);
    gl_lds16(gB1 + ko, dB1);
    __syncthreads();
    h8_t af[4], bf[4];
#pragma unroll
    for (int m = 0; m < 4; m++) af[m] = *(const h8_t*)(As + (rA + m * 16) * 32 + kb);
#pragma unroll
    for (int n = 0; n < 4; n++) bf[n] = *(const h8_t*)(Bs + (rB + n * 16) * 32 + kb);
#pragma unroll
    for (int m = 0; m < 4; m++)
#pragma unroll
      for (int n = 0; n < 4; n++)
        acc[m][n] = __builtin_amdgcn_mfma_f32_16x16x32_f16(af[m], bf[n], acc[m][n], 0, 0, 0);
    __syncthreads();
  }
}

// ---------- GEMM with transposed per-chain store ----------
// mode 0 (xg): out[((b*3 + g)*128 + j)*2048 + t],  g = col>>7 (N=384)
// mode 1 (xf): out[((g*64 + b)*128 + j)*2048 + t],  g = col>>7 (N=256)
__global__ __launch_bounds__(256) void gemm_xT_kernel(
    const f16* __restrict__ A, int lda,
    const f16* __restrict__ Bw, int ldb,
    const float* __restrict__ bias,
    f16* __restrict__ out, int ksteps, int mode)
{
  __shared__ f16 As[4096];
  __shared__ f16 Bs[4096];
  f4_t acc[4][4];
#pragma unroll
  for (int m = 0; m < 4; m++)
#pragma unroll
    for (int n = 0; n < 4; n++) acc[m][n] = f4_t{0.f, 0.f, 0.f, 0.f};

  const f16* Ab = A + (size_t)blockIdx.x * 128 * lda;
  const f16* Bb = Bw + (size_t)blockIdx.y * 128 * ldb;
  kloop128(Ab, lda, Bb, ldb, ksteps, As, Bs, acc);

  const int tid = threadIdx.x, wave = tid >> 6, lane = tid & 63;
  const int col0 = blockIdx.y * 128 + (wave & 1) * 64 + (lane & 15);
  const int row0 = blockIdx.x * 128 + (wave >> 1) * 64 + (lane >> 4) * 4;
  const int b = blockIdx.x >> 4;   // 16 row-blocks per batch (2048/128)
#pragma unroll
  for (int n = 0; n < 4; n++) {
    const int col = col0 + n * 16;
    const float bv = bias[col];
    const int g = col >> 7, jj = col & 127;
    const size_t base = (mode == 0)
        ? ((size_t)((b * 3 + g) * 128 + jj)) * 2048
        : ((size_t)((g * 64 + b) * 128 + jj)) * 2048;
#pragma unroll
    for (int m = 0; m < 4; m++) {
      const int row = row0 + m * 16;
      const int t = row & 2047;
      h4_t v = h4_t{(f16)(acc[m][n][0] + bv), (f16)(acc[m][n][1] + bv),
                    (f16)(acc[m][n][2] + bv), (f16)(acc[m][n][3] + bv)};
      *(h4_t*)(out + base + t) = v;
    }
  }
}

// ---------- conv: sum of 3 relu'd GEMM segments (row-major out) ----------
__global__ __launch_bounds__(256) void conv3sum_kernel(
    const f16* __restrict__ A5,
    const f16* __restrict__ W5p, const f16* __restrict__ W3p, const f16* __restrict__ W1p,
    const float* __restrict__ b5, const float* __restrict__ b3, const float* __restrict__ b1,
    f16* __restrict__ oc)
{
  __shared__ f16 As[4096];
  __shared__ f16 Bs[4096];
  const int tid = threadIdx.x, wave = tid >> 6, lane = tid & 63;
  const int col0 = blockIdx.y * 128 + (wave & 1) * 64 + (lane & 15);
  const int row0 = blockIdx.x * 128 + (wave >> 1) * 64 + (lane >> 4) * 4;
  const f16* Ab = A5 + (size_t)blockIdx.x * 128 * 480;

  f4_t tot[4][4];
#pragma unroll
  for (int m = 0; m < 4; m++)
#pragma unroll
    for (int n = 0; n < 4; n++) tot[m][n] = f4_t{0.f, 0.f, 0.f, 0.f};

  auto seg = [&](const f16* Wp, int ldb, int ks, int aoff, const float* bias) {
    f4_t acc[4][4];
#pragma unroll
    for (int m = 0; m < 4; m++)
#pragma unroll
      for (int n = 0; n < 4; n++) acc[m][n] = f4_t{0.f, 0.f, 0.f, 0.f};
    kloop128(Ab + aoff, 480, Wp + (size_t)blockIdx.y * 128 * ldb, ldb, ks, As, Bs, acc);
#pragma unroll
    for (int n = 0; n < 4; n++) {
      const float bv = bias[col0 + n * 16];
#pragma unroll
      for (int m = 0; m < 4; m++)
#pragma unroll
        for (int q = 0; q < 4; q++)
          tot[m][n][q] += fmaxf(acc[m][n][q] + bv, 0.f);
    }
  };
  seg(W5p, 480, 15, 0,   b5);
  seg(W3p, 288, 9,  96,  b3);
  seg(W1p, 96,  3,  192, b1);

#pragma unroll
  for (int n = 0; n < 4; n++) {
    const int col = col0 + n * 16;
#pragma unroll
    for (int m = 0; m < 4; m++) {
      const int row = row0 + m * 16;
#pragma unroll
      for (int q = 0; q < 4; q++)
        oc[(size_t)(row + q) * 256 + col] = (f16)tot[m][n][q];
    }
  }
}

// ---------- im2col ----------
__global__ __launch_bounds__(384) void im2col_kernel(
    const float* __restrict__ x, f16* __restrict__ A5)
{
  const int tid = threadIdx.x;
  const int r = tid / 12, c8 = tid % 12;
  const int bt = blockIdx.x * 32 + r;
  const int kg = blockIdx.y;
  const int b = bt >> 11, t = bt & 2047;
  const int ts = t + kg - 2;
  h8_t v = {0, 0, 0, 0, 0, 0, 0, 0};
  if (c8 < 10 && (unsigned)ts < 2048u) {
    const float* src = x + ((size_t)(b << 11) + ts) * 80 + c8 * 8;
    f4_t a = *(const f4_t*)src;
    f4_t bvec = *(const f4_t*)(src + 4);
    v = h8_t{(f16)a[0], (f16)a[1], (f16)a[2], (f16)a[3],
             (f16)bvec[0], (f16)bvec[1], (f16)bvec[2], (f16)bvec[3]};
  }
  *(h8_t*)(A5 + (size_t)bt * 480 + kg * 96 + c8 * 8) = v;
}

// ---------- weight packing ----------
__global__ void pack_convw_kernel(
    const float* __restrict__ w1, const float* __restrict__ w3,
    const float* __restrict__ w5, const float* __restrict__ fc1w,
    f16* __restrict__ W5p, f16* __restrict__ W3p, f16* __restrict__ W1p,
    f16* __restrict__ FC1p)
{
  const int col = blockIdx.x;
  const int c = threadIdx.x;
  if (col < 480) {
    const int kg = col / 96, d = col % 96;
    W5p[c * 480 + col] = (f16)((d < 80) ? w5[(c * 80 + d) * 5 + kg] : 0.f);
  } else if (col < 768) {
    const int cc = col - 480, k = cc / 96, d = cc % 96;
    W3p[c * 288 + cc] = (f16)((d < 80) ? w3[(c * 80 + d) * 3 + k] : 0.f);
  } else if (col < 864) {
    const int d = col - 768;
    W1p[c * 96 + d] = (f16)((d < 80) ? w1[c * 80 + d] : 0.f);
  } else {
    const int d = col - 864;
    FC1p[c * 96 + d] = (f16)((d < 80) ? fc1w[c * 80 + d] : 0.f);
  }
}

__global__ void cast_f16_kernel(const float* __restrict__ src, f16* __restrict__ dst, int n8)
{
  const int i = blockIdx.x * blockDim.x + threadIdx.x;
  if (i >= n8) return;
  f4_t a = *(const f4_t*)(src + (size_t)i * 8);
  f4_t b = *(const f4_t*)(src + (size_t)i * 8 + 4);
  h8_t v = h8_t{(f16)a[0], (f16)a[1], (f16)a[2], (f16)a[3],
                (f16)b[0], (f16)b[1], (f16)b[2], (f16)b[3]};
  *(h8_t*)(dst + (size_t)i * 8) = v;
}

// ---------- GRU recurrence v9: MFMA-batched, 16 chains/block, 8 blocks ------
// hb layout: [buf][kt][row=chain 16][klo 32] f16, octet-swizzled:
//   elem (row, k): kt=k>>5, oct=((k&31)>>3)^((row>>1)&3), off=k&7
// A-frag read (verified m97 pattern): row=lane&15, octet base=lane>>4 -> all 64
// 16B chunks distinct -> conflict-free.
template<int L1>
__global__ __launch_bounds__(512, 1) void gru_rec9_kernel(
    const f16* __restrict__ xgT,   // [d][b][g][j][t]
    const f16* __restrict__ whh16, // layer base, f16 [d][384][128]
    const float* __restrict__ bhh, // layer base [d][384]
    const f16* __restrict__ xfT,   // [d][b][j][t] (L1 only)
    f16* __restrict__ h0out,       // [b][t][256] (L0)
    float* __restrict__ ogout)     // [b][t][256] f32 (L1)
{
  const int bg = blockIdx.x;       // batch group 0..3 (16 chains each)
  const int d  = blockIdx.y;       // direction
  const int tid = threadIdx.x, w = tid >> 6, lane = tid & 63;
  const int nl = lane & 15, mg = lane >> 4;
  const int jcol = w * 16 + nl;    // 0..127 (this lane's output column)
  const int m0 = mg * 4;           // first chain of this lane's D rows
  const int b0 = bg * 16;

  // B-fragments (weights) - 12 h8_t = 48 VGPR
  const f16* whh_d = whh16 + (size_t)d * 49152;
  h8_t WB[3][4];
#pragma unroll
  for (int g = 0; g < 3; g++)
#pragma unroll
    for (int kt = 0; kt < 4; kt++)
      WB[g][kt] = *(const h8_t*)(whh_d + (size_t)(g * 128 + jcol) * 128 + kt * 32 + mg * 8);
  const float br = bhh[d * 384 + jcol];
  const float bz = bhh[d * 384 + 128 + jcol];
  const float bn = bhh[d * 384 + 256 + jcol];

  __shared__ __align__(16) f16 hb[8192];   // 2 bufs x 4 kt x 16 x 32
  for (int i = tid; i < 8192; i += 512) hb[i] = (f16)0.f;
  float hst[4] = {0.f, 0.f, 0.f, 0.f};

  const int mt   = d ? 2047 : 0;
  const int mtb4 = d ? 2044 : 0;

  // x pointers: chain (d*64 + b0 + m0 + q), gate stride 262144, j stride 2048
  const f16* xg_l = xgT + (size_t)(d * 64 + b0 + m0) * 786432 + (size_t)jcol * 2048;
  const f16* xf_l = L1 ? (xfT + (size_t)(d * 64 + b0 + m0) * 262144 + (size_t)jcol * 2048)
                       : nullptr;
  f16*   h0_l = L1 ? nullptr : (h0out + (size_t)(b0 + m0) * 524288 + d * 128 + jcol);
  float* og_l = L1 ? (ogout + (size_t)(b0 + m0) * 524288 + d * 128 + jcol) : nullptr;

  // A-frag read offset (f16 units), octet swizzle by row=nl
  const int rd_off = nl * 32 + ((mg ^ ((nl >> 1) & 3)) * 8);

  // x prefetch: 4-step groups, h4_t per (chain q, gate)
  h4_t xr0[4], xz0[4], xn0[4], xf0[4];
  h4_t xr1[4], xz1[4], xn1[4], xf1[4];
  auto ldgrp = [&](h4_t (&xr)[4], h4_t (&xz)[4], h4_t (&xn)[4], h4_t (&xf)[4], int s4) {
    const int tb = s4 ^ mtb4;
#pragma unroll
    for (int q = 0; q < 4; q++) {
      const f16* p = xg_l + (size_t)q * 786432 + tb;
      xr[q] = *(const h4_t*)(p);
      xz[q] = *(const h4_t*)(p + 262144);
      xn[q] = *(const h4_t*)(p + 524288);
      if (L1) xf[q] = *(const h4_t*)(xf_l + (size_t)q * 262144 + tb);
    }
  };

  ldgrp(xr0, xz0, xn0, xf0, 0);
  __syncthreads();

#define STEP9(SG, SS, XR, XZ, XN, XF)                                              \
  {                                                                                \
    const int buf = (SS) & 1;                                                      \
    const int t = (SG) ^ mt;                                                       \
    h8_t hv[4];                                                                    \
    _Pragma("unroll")                                                              \
    for (int kt = 0; kt < 4; kt++)                                                 \
      hv[kt] = *(const h8_t*)(hb + buf * 2048 + kt * 512 + rd_off);                \
    f4_t aR = {0.f, 0.f, 0.f, 0.f}, aZ = aR, aN = aR;                              \
    _Pragma("unroll")                                                              \
    for (int kt = 0; kt < 4; kt++) {                                               \
      aR = __builtin_amdgcn_mfma_f32_16x16x32_f16(hv[kt], WB[0][kt], aR, 0, 0, 0); \
      aZ = __builtin_amdgcn_mfma_f32_16x16x32_f16(hv[kt], WB[1][kt], aZ, 0, 0, 0); \
      aN = __builtin_amdgcn_mfma_f32_16x16x32_f16(hv[kt], WB[2][kt], aN, 0, 0, 0); \
    }                                                                              \
    _Pragma("unroll")                                                              \
    for (int q = 0; q < 4; q++) {                                                  \
      const float xrv = d ? (float)XR[q][3 - ((SS) & 3)] : (float)XR[q][(SS) & 3]; \
      const float xzv = d ? (float)XZ[q][3 - ((SS) & 3)] : (float)XZ[q][(SS) & 3]; \
      const float xnv = d ? (float)XN[q][3 - ((SS) & 3)] : (float)XN[q][(SS) & 3]; \
      const float rr = fastrcp(1.f + fastex2((xrv + aR[q] + br) * -1.44269504f));  \
      const float zz = fastrcp(1.f + fastex2((xzv + aZ[q] + bz) * -1.44269504f));  \
      const float na = xnv + rr * (aN[q] + bn);                                    \
      const float ex = fastex2(fabsf(na) * 2.88539008f);                           \
      const float th = copysignf(1.f - 2.f * fastrcp(ex + 1.f), na);               \
      const float hn = (1.f - zz) * th + zz * hst[q];                              \
      hst[q] = hn;                                                                 \
      const int mrow = m0 + q;                                                     \
      const int oct = ((jcol & 31) >> 3) ^ ((mrow >> 1) & 3);                      \
      hb[(buf ^ 1) * 2048 + (jcol >> 5) * 512 + mrow * 32 + oct * 8 + (jcol & 7)]  \
          = (f16)hn;                                                               \
      if (L1) og_l[(size_t)q * 524288 + (size_t)t * 256] =                         \
          hn + (d ? (float)XF[q][3 - ((SS) & 3)] : (float)XF[q][(SS) & 3]);        \
      else h0_l[(size_t)q * 524288 + (size_t)t * 256] = (f16)hn;                   \
    }                                                                              \
    asm volatile("s_waitcnt lgkmcnt(0)" ::: "memory");                             \
    __builtin_amdgcn_s_barrier();                                                  \
    __builtin_amdgcn_sched_barrier(0);                                             \
  }

  for (int s8 = 0; s8 < T_; s8 += 8) {
    ldgrp(xr1, xz1, xn1, xf1, s8 + 4);
    STEP9(s8 + 0, 0, xr0, xz0, xn0, xf0);
    STEP9(s8 + 1, 1, xr0, xz0, xn0, xf0);
    STEP9(s8 + 2, 2, xr0, xz0, xn0, xf0);
    STEP9(s8 + 3, 3, xr0, xz0, xn0, xf0);
    if (s8 + 8 < T_) ldgrp(xr0, xz0, xn0, xf0, s8 + 8);
    STEP9(s8 + 4, 0, xr1, xz1, xn1, xf1);
    STEP9(s8 + 5, 1, xr1, xz1, xn1, xf1);
    STEP9(s8 + 6, 2, xr1, xz1, xn1, xf1);
    STEP9(s8 + 7, 3, xr1, xz1, xn1, xf1);
  }
#undef STEP9
}

// ---------- final head ----------
__global__ __launch_bounds__(256) void fc_out_kernel(
    const float* __restrict__ og, const float* __restrict__ fcw,
    const float* __restrict__ fcb, float* __restrict__ out)
{
  const int lane = threadIdx.x & 63;
  const int wid = (blockIdx.x * 256 + threadIdx.x) >> 6;
  const int nw = (gridDim.x * 256) >> 6;
  const f4_t w0 = *(const f4_t*)(fcw + 0 * 256 + lane * 4);
  const f4_t w1 = *(const f4_t*)(fcw + 1 * 256 + lane * 4);
  const f4_t w2 = *(const f4_t*)(fcw + 2 * 256 + lane * 4);
  const f4_t w3 = *(const f4_t*)(fcw + 3 * 256 + lane * 4);
  const float b0 = fcb[0], b1 = fcb[1], b2 = fcb[2], b3 = fcb[3];
  for (int row = wid; row < BT_; row += nw) {
    const f4_t v = *(const f4_t*)(og + (size_t)row * 256 + lane * 4);
    float p0 = v[0] * w0[0] + v[1] * w0[1] + v[2] * w0[2] + v[3] * w0[3];
    float p1 = v[0] * w1[0] + v[1] * w1[1] + v[2] * w1[2] + v[3] * w1[3];
    float p2 = v[0] * w2[0] + v[1] * w2[1] + v[2] * w2[2] + v[3] * w2[3];
    float p3 = v[0] * w3[0] + v[1] * w3[1] + v[2] * w3[2] + v[3] * w3[3];
#pragma unroll
    for (int off = 1; off < 64; off <<= 1) {
      p0 += __shfl_xor(p0, off);
      p1 += __shfl_xor(p1, off);
      p2 += __shfl_xor(p2, off);
      p3 += __shfl_xor(p3, off);
    }
    if (lane == 0) {
      f4_t o4 = f4_t{p0 + b0, p1 + b1, p2 + b2, p3 + b3};
      *(f4_t*)(out + (size_t)row * 4) = o4;
    }
  }
}

extern "C" void kernel_launch(void* const* d_in, const int* in_sizes, int n_in,
                              void* d_out, int out_size, void* d_ws, size_t ws_size,
                              hipStream_t stream)
{
  const float* x       = (const float*)d_in[0];
  const float* conv1_w = (const float*)d_in[1];
  const float* conv1_b = (const float*)d_in[2];
  const float* conv3_w = (const float*)d_in[3];
  const float* conv3_b = (const float*)d_in[4];
  const float* conv5_w = (const float*)d_in[5];
  const float* conv5_b = (const float*)d_in[6];
  const float* fc1_w   = (const float*)d_in[7];
  const float* fc1_b   = (const float*)d_in[8];
  const float* fc_w    = (const float*)d_in[9];
  const float* fc_b    = (const float*)d_in[10];
  const float* gru_wih = (const float*)d_in[11];
  const float* gru_whh = (const float*)d_in[12];
  const float* gru_bih = (const float*)d_in[13];
  const float* gru_bhh = (const float*)d_in[14];

  size_t off = 0;
  auto alloc = [&](size_t bytes) {
    char* p = (char*)d_ws + off;
    off += (bytes + 255) & ~(size_t)255;
    return p;
  };
  f16* A5   = (f16*)alloc((size_t)BT_ * 480 * 2);
  f16* W5p  = (f16*)alloc(256 * 480 * 2);
  f16* W3p  = (f16*)alloc(256 * 288 * 2);
  f16* W1p  = (f16*)alloc(256 * 96 * 2);
  f16* FC1p = (f16*)alloc(256 * 96 * 2);
  f16* wihp = (f16*)alloc(4ull * 384 * 256 * 2);
  f16* whhp = (f16*)alloc(4ull * 384 * 128 * 2);
  f16* oc   = (f16*)alloc((size_t)BT_ * 256 * 2);
  f16* xgT  = (f16*)alloc(2ull * 64 * 3 * 128 * 2048 * 2);
  f16* h0   = (f16*)alloc((size_t)BT_ * 256 * 2);
  f16* xfT  = (f16*)alloc(2ull * 64 * 128 * 2048 * 2);
  if (off > ws_size) return;

  float* og   = (float*)d_out;
  float* out2 = (float*)d_out + OG_ELEMS;

  im2col_kernel<<<dim3(BT_ / 32, 5), 384, 0, stream>>>(x, A5);
  pack_convw_kernel<<<960, 256, 0, stream>>>(conv1_w, conv3_w, conv5_w, fc1_w,
                                             W5p, W3p, W1p, FC1p);
  cast_f16_kernel<<<(49152 + 255) / 256, 256, 0, stream>>>(gru_wih, wihp, 49152);
  cast_f16_kernel<<<(24576 + 255) / 256, 256, 0, stream>>>(gru_whh, whhp, 24576);

  conv3sum_kernel<<<dim3(1024, 2), 256, 0, stream>>>(A5, W5p, W3p, W1p,
                                                     conv5_b, conv3_b, conv1_b, oc);
  // fc1 residual path -> transposed chain layout
  gemm_xT_kernel<<<dim3(1024, 2), 256, 0, stream>>>(A5 + 192, 480, FC1p, 96,
                                                    fc1_b, xfT, 3, 1);

  for (int l = 0; l < 2; ++l) {
    const f16* hin = l ? h0 : oc;
    for (int d = 0; d < 2; ++d) {
      gemm_xT_kernel<<<dim3(1024, 3), 256, 0, stream>>>(
          hin, 256, wihp + (size_t)(l * 2 + d) * 384 * 256, 256,
          gru_bih + (l * 2 + d) * 384,
          xgT + (size_t)d * 64 * 3 * 128 * 2048, 8, 0);
    }
    if (l == 0)
      gru_rec9_kernel<0><<<dim3(4, 2), 512, 0, stream>>>(
          xgT, whhp, gru_bhh, nullptr, h0, nullptr);
    else
      gru_rec9_kernel<1><<<dim3(4, 2), 512, 0, stream>>>(
          xgT, whhp + 2 * 49152, gru_bhh + 2 * 384, xfT, nullptr, og);
  }

  fc_out_kernel<<<1024, 256, 0, stream>>>(og, fc_w, fc_b, out2);
}

// Round 10
// 2215.468 us; speedup vs baseline: 3.6491x; 3.6491x over previous
//
#include <hip/hip_runtime.h>
#include <hip/hip_bf16.h>
#include <hip/hip_fp16.h>

typedef _Float16 f16;
typedef _Float16 h2_t __attribute__((ext_vector_type(2)));
typedef _Float16 h4_t __attribute__((ext_vector_type(4)));
typedef _Float16 h8_t __attribute__((ext_vector_type(8)));
typedef float    f4_t __attribute__((ext_vector_type(4)));
typedef int      i4_t __attribute__((ext_vector_type(4)));

#define B_  64
#define T_  2048
#define BT_ 131072   // B_*T_
#define OG_ELEMS 33554432ull  // BT_*256

// ---------- async global->LDS (16B per lane, wave-uniform LDS base) ----------
__device__ __forceinline__ void gl_lds16(const void* g, void* lds) {
  __builtin_amdgcn_global_load_lds(
      (const __attribute__((address_space(1))) void*)g,
      (__attribute__((address_space(3))) void*)lds, 16, 0, 0);
}

__device__ __forceinline__ float fastrcp(float x)  { return __builtin_amdgcn_rcpf(x); }
__device__ __forceinline__ float fastex2(float x)  { return __builtin_amdgcn_exp2f(x); }

// register-only pair swap (lane ^ 1) via DPP quad_perm [1,0,3,2]
__device__ __forceinline__ float dpp_swap1(float x) {
  int i = __builtin_bit_cast(int, x);
  int y = __builtin_amdgcn_update_dpp(0, i, 0xB1, 0xF, 0xF, true);
  return __builtin_bit_cast(float, y);
}

// ---------- m97-style K-loop: 128x128 tile, BK=32, f16 MFMA ----------
__device__ __forceinline__ void kloop128(
    const f16* __restrict__ Ab, int lda,
    const f16* __restrict__ Bb, int ldb,
    int ksteps, f16* As, f16* Bs, f4_t (&acc)[4][4])
{
  const int tid  = threadIdx.x;
  const int wave = tid >> 6, lane = tid & 63;
  const int srow = tid >> 2;
  const int scol = (tid & 3) * 8;
  const int fr   = lane & 15;
  const int kb   = (lane >> 4) * 8;
  const int rA   = (wave >> 1) * 64 + fr;
  const int rB   = (wave & 1) * 64 + fr;

  f16* dA0 = As + wave * 512;
  f16* dA1 = As + 2048 + wave * 512;
  f16* dB0 = Bs + wave * 512;
  f16* dB1 = Bs + 2048 + wave * 512;
  const f16* gA0 = Ab + (size_t)srow * lda + scol;
  const f16* gA1 = Ab + (size_t)(srow + 64) * lda + scol;
  const f16* gB0 = Bb + (size_t)srow * ldb + scol;
  const f16* gB1 = Bb + (size_t)(srow + 64) * ldb + scol;

  for (int kt = 0; kt < ksteps; ++kt) {
    const int ko = kt * 32;
    gl_lds16(gA0 + ko, dA0);
    gl_lds16(gA1 + ko, dA1);
    gl_lds16(gB0 + ko, dB0);
    gl_lds16(gB1 + ko, dB1);
    __syncthreads();
    h8_t af[4], bf[4];
#pragma unroll
    for (int m = 0; m < 4; m++) af[m] = *(const h8_t*)(As + (rA + m * 16) * 32 + kb);
#pragma unroll
    for (int n = 0; n < 4; n++) bf[n] = *(const h8_t*)(Bs + (rB + n * 16) * 32 + kb);
#pragma unroll
    for (int m = 0; m < 4; m++)
#pragma unroll
      for (int n = 0; n < 4; n++)
        acc[m][n] = __builtin_amdgcn_mfma_f32_16x16x32_f16(af[m], bf[n], acc[m][n], 0, 0, 0);
    __syncthreads();
  }
}

// ---------- GEMM with transposed per-chain store ----------
// mode 0 (xg): out[((b*3 + g)*128 + j)*2048 + t],  g = col>>7 (N=384)
// mode 1 (xf): out[((g*64 + b)*128 + j)*2048 + t],  g = col>>7 (N=256)
__global__ __launch_bounds__(256) void gemm_xT_kernel(
    const f16* __restrict__ A, int lda,
    const f16* __restrict__ Bw, int ldb,
    const float* __restrict__ bias,
    f16* __restrict__ out, int ksteps, int mode)
{
  __shared__ f16 As[4096];
  __shared__ f16 Bs[4096];
  f4_t acc[4][4];
#pragma unroll
  for (int m = 0; m < 4; m++)
#pragma unroll
    for (int n = 0; n < 4; n++) acc[m][n] = f4_t{0.f, 0.f, 0.f, 0.f};

  const f16* Ab = A + (size_t)blockIdx.x * 128 * lda;
  const f16* Bb = Bw + (size_t)blockIdx.y * 128 * ldb;
  kloop128(Ab, lda, Bb, ldb, ksteps, As, Bs, acc);

  const int tid = threadIdx.x, wave = tid >> 6, lane = tid & 63;
  const int col0 = blockIdx.y * 128 + (wave & 1) * 64 + (lane & 15);
  const int row0 = blockIdx.x * 128 + (wave >> 1) * 64 + (lane >> 4) * 4;
  const int b = blockIdx.x >> 4;   // 16 row-blocks per batch (2048/128)
#pragma unroll
  for (int n = 0; n < 4; n++) {
    const int col = col0 + n * 16;
    const float bv = bias[col];
    const int g = col >> 7, jj = col & 127;
    const size_t base = (mode == 0)
        ? ((size_t)((b * 3 + g) * 128 + jj)) * 2048
        : ((size_t)((g * 64 + b) * 128 + jj)) * 2048;
#pragma unroll
    for (int m = 0; m < 4; m++) {
      const int row = row0 + m * 16;
      const int t = row & 2047;
      h4_t v = h4_t{(f16)(acc[m][n][0] + bv), (f16)(acc[m][n][1] + bv),
                    (f16)(acc[m][n][2] + bv), (f16)(acc[m][n][3] + bv)};
      *(h4_t*)(out + base + t) = v;
    }
  }
}

// ---------- conv: sum of 3 relu'd GEMM segments (row-major out) ----------
__global__ __launch_bounds__(256) void conv3sum_kernel(
    const f16* __restrict__ A5,
    const f16* __restrict__ W5p, const f16* __restrict__ W3p, const f16* __restrict__ W1p,
    const float* __restrict__ b5, const float* __restrict__ b3, const float* __restrict__ b1,
    f16* __restrict__ oc)
{
  __shared__ f16 As[4096];
  __shared__ f16 Bs[4096];
  const int tid = threadIdx.x, wave = tid >> 6, lane = tid & 63;
  const int col0 = blockIdx.y * 128 + (wave & 1) * 64 + (lane & 15);
  const int row0 = blockIdx.x * 128 + (wave >> 1) * 64 + (lane >> 4) * 4;
  const f16* Ab = A5 + (size_t)blockIdx.x * 128 * 480;

  f4_t tot[4][4];
#pragma unroll
  for (int m = 0; m < 4; m++)
#pragma unroll
    for (int n = 0; n < 4; n++) tot[m][n] = f4_t{0.f, 0.f, 0.f, 0.f};

  auto seg = [&](const f16* Wp, int ldb, int ks, int aoff, const float* bias) {
    f4_t acc[4][4];
#pragma unroll
    for (int m = 0; m < 4; m++)
#pragma unroll
      for (int n = 0; n < 4; n++) acc[m][n] = f4_t{0.f, 0.f, 0.f, 0.f};
    kloop128(Ab + aoff, 480, Wp + (size_t)blockIdx.y * 128 * ldb, ldb, ks, As, Bs, acc);
#pragma unroll
    for (int n = 0; n < 4; n++) {
      const float bv = bias[col0 + n * 16];
#pragma unroll
      for (int m = 0; m < 4; m++)
#pragma unroll
        for (int q = 0; q < 4; q++)
          tot[m][n][q] += fmaxf(acc[m][n][q] + bv, 0.f);
    }
  };
  seg(W5p, 480, 15, 0,   b5);
  seg(W3p, 288, 9,  96,  b3);
  seg(W1p, 96,  3,  192, b1);

#pragma unroll
  for (int n = 0; n < 4; n++) {
    const int col = col0 + n * 16;
#pragma unroll
    for (int m = 0; m < 4; m++) {
      const int row = row0 + m * 16;
#pragma unroll
      for (int q = 0; q < 4; q++)
        oc[(size_t)(row + q) * 256 + col] = (f16)tot[m][n][q];
    }
  }
}

// ---------- im2col ----------
__global__ __launch_bounds__(384) void im2col_kernel(
    const float* __restrict__ x, f16* __restrict__ A5)
{
  const int tid = threadIdx.x;
  const int r = tid / 12, c8 = tid % 12;
  const int bt = blockIdx.x * 32 + r;
  const int kg = blockIdx.y;
  const int b = bt >> 11, t = bt & 2047;
  const int ts = t + kg - 2;
  h8_t v = {0, 0, 0, 0, 0, 0, 0, 0};
  if (c8 < 10 && (unsigned)ts < 2048u) {
    const float* src = x + ((size_t)(b << 11) + ts) * 80 + c8 * 8;
    f4_t a = *(const f4_t*)src;
    f4_t bvec = *(const f4_t*)(src + 4);
    v = h8_t{(f16)a[0], (f16)a[1], (f16)a[2], (f16)a[3],
             (f16)bvec[0], (f16)bvec[1], (f16)bvec[2], (f16)bvec[3]};
  }
  *(h8_t*)(A5 + (size_t)bt * 480 + kg * 96 + c8 * 8) = v;
}

// ---------- weight packing ----------
__global__ void pack_convw_kernel(
    const float* __restrict__ w1, const float* __restrict__ w3,
    const float* __restrict__ w5, const float* __restrict__ fc1w,
    f16* __restrict__ W5p, f16* __restrict__ W3p, f16* __restrict__ W1p,
    f16* __restrict__ FC1p)
{
  const int col = blockIdx.x;
  const int c = threadIdx.x;
  if (col < 480) {
    const int kg = col / 96, d = col % 96;
    W5p[c * 480 + col] = (f16)((d < 80) ? w5[(c * 80 + d) * 5 + kg] : 0.f);
  } else if (col < 768) {
    const int cc = col - 480, k = cc / 96, d = cc % 96;
    W3p[c * 288 + cc] = (f16)((d < 80) ? w3[(c * 80 + d) * 3 + k] : 0.f);
  } else if (col < 864) {
    const int d = col - 768;
    W1p[c * 96 + d] = (f16)((d < 80) ? w1[c * 80 + d] : 0.f);
  } else {
    const int d = col - 864;
    FC1p[c * 96 + d] = (f16)((d < 80) ? fc1w[c * 80 + d] : 0.f);
  }
}

__global__ void cast_f16_kernel(const float* __restrict__ src, f16* __restrict__ dst, int n8)
{
  const int i = blockIdx.x * blockDim.x + threadIdx.x;
  if (i >= n8) return;
  f4_t a = *(const f4_t*)(src + (size_t)i * 8);
  f4_t b = *(const f4_t*)(src + (size_t)i * 8 + 4);
  h8_t v = h8_t{(f16)a[0], (f16)a[1], (f16)a[2], (f16)a[3],
                (f16)b[0], (f16)b[1], (f16)b[2], (f16)b[3]};
  *(h8_t*)(dst + (size_t)i * 8) = v;
}

// ---------- GRU recurrence v10: v7 + VALU diet (subreg dots, split stores) ---
__device__ __forceinline__ float fd2(int h, int w, float acc) {
  return __builtin_amdgcn_fdot2(__builtin_bit_cast(h2_t, h),
                                __builtin_bit_cast(h2_t, w), acc, false);
}

// one i4_t = 8 f16 (4 x h2 pairs)
#define DOTQ(acc0, acc1, hq, wq)            \
  do {                                      \
    acc0 = fd2(hq[0], wq[0], acc0);         \
    acc1 = fd2(hq[1], wq[1], acc1);         \
    acc0 = fd2(hq[2], wq[2], acc0);         \
    acc1 = fd2(hq[3], wq[3], acc1);         \
  } while (0)

template<int DIR, int L1>
__device__ __forceinline__ void gru_chain(
    const f16* __restrict__ xg_b,   // + (d*64+b)*3*128*2048
    const f16* __restrict__ xf_b,   // + (d*64+b)*128*2048   (L1 only)
    const f16* __restrict__ whh_d,  // packed f16, this dir (384*128)
    const float* __restrict__ bhh_d,
    f16* __restrict__ h0_b,         // + b*2048*256 + d*128 + j  (L0)
    float* __restrict__ og_b)       // same offset                (L1)
{
  const int tid  = threadIdx.x;      // 256
  const int wv   = tid >> 6;
  const int lane = tid & 63;
  const int j    = wv * 32 + (lane >> 1);   // 0..127 output unit
  const int kh   = lane & 1;                // K-half owner
  const int co   = kh * 64;

  // weights: rows j (r), 128+j (z), 256+j (n); cols [kh*64, kh*64+64)
  i4_t WR[8], WZ[8], WN[8];
#pragma unroll
  for (int q = 0; q < 8; q++) WR[q] = *(const i4_t*)(whh_d + (size_t)j * 128 + co + q * 8);
#pragma unroll
  for (int q = 0; q < 8; q++) WZ[q] = *(const i4_t*)(whh_d + (size_t)(128 + j) * 128 + co + q * 8);
#pragma unroll
  for (int q = 0; q < 8; q++) WN[q] = *(const i4_t*)(whh_d + (size_t)(256 + j) * 128 + co + q * 8);
  const float br = bhh_d[j], bz = bhh_d[128 + j], bn = bhh_d[256 + j];

  __shared__ __align__(16) f16 hb[2][128];
  if (tid < 128) { hb[0][tid] = (f16)0.f; hb[1][tid] = (f16)0.f; }
  float hstate = 0.f;

  // incremental output pointers (kh==1 lane stores to global)
  const int t0 = DIR ? (T_ - 1) : 0;
  f16*   h0p = L1 ? nullptr : (h0_b + (size_t)t0 * 256);
  float* ogp = L1 ? (og_b + (size_t)t0 * 256) : nullptr;
  const int pstep = DIR ? -256 : 256;

  h8_t xrA{}, xzA{}, xnA{}, xfA{};
  h8_t xrB{}, xzB{}, xnB{}, xfB{};
  auto ld4 = [&](int s8, h8_t& xr, h8_t& xz, h8_t& xn, h8_t& xf) {
    const int tb = DIR ? (T_ - 8 - s8) : s8;
    xr = *(const h8_t*)(xg_b + (size_t)(0 * 128 + j) * 2048 + tb);
    xz = *(const h8_t*)(xg_b + (size_t)(1 * 128 + j) * 2048 + tb);
    xn = *(const h8_t*)(xg_b + (size_t)(2 * 128 + j) * 2048 + tb);
    if (L1) xf = *(const h8_t*)(xf_b + (size_t)j * 2048 + tb);
  };
  ld4(0, xrA, xzA, xnA, xfA);
  asm volatile("s_waitcnt lgkmcnt(0)" ::: "memory");
  __builtin_amdgcn_s_barrier();

  for (int s8 = 0; s8 < T_; s8 += 8) {
    if ((s8 + 8) < T_) ld4(s8 + 8, xrB, xzB, xnB, xfB);
#pragma unroll
    for (int ss = 0; ss < 8; ss++) {
      const int e = DIR ? (7 - ss) : ss;
      // --- read h K-half from current buffer (as u32 quads) ---
      const f16* hbuf = &hb[ss & 1][0] + co;
      i4_t hv[8];
#pragma unroll
      for (int q = 0; q < 8; q++) hv[q] = *(const i4_t*)(hbuf + q * 8);
      // --- 3-gate half-dots, 6 accumulator chains, subreg h2 access ---
      float r0 = 0.f, r1 = 0.f, z0 = 0.f, z1 = 0.f, n0 = 0.f, n1 = 0.f;
#pragma unroll
      for (int q = 0; q < 8; q++) {
        DOTQ(r0, r1, hv[q], WR[q]);
        DOTQ(z0, z1, hv[q], WZ[q]);
        DOTQ(n0, n1, hv[q], WN[q]);
      }
      float sr = r0 + r1; sr += dpp_swap1(sr);
      float sz = z0 + z1; sz += dpp_swap1(sz);
      float sn = n0 + n1; sn += dpp_swap1(sn);
      // --- gates (redundant on both pair lanes; no divergence) ---
      const float rr = fastrcp(1.f + fastex2(((float)xrA[e] + sr + br) * -1.44269504f));
      const float zz = fastrcp(1.f + fastex2(((float)xzA[e] + sz + bz) * -1.44269504f));
      const float na = (float)xnA[e] + rr * (sn + bn);
      const float ex = fastex2(fabsf(na) * 2.88539008f);
      const float th = copysignf(1.f - 2.f * fastrcp(ex + 1.f), na);
      hstate = (1.f - zz) * th + zz * hstate;
      // --- split stores across the pair: kh0 -> LDS, kh1 -> global ---
      if (!kh) {
        hb[(ss & 1) ^ 1][j] = (f16)hstate;
      } else {
        if (L1) ogp[0] = hstate + (float)xfA[e];
        else    h0p[0] = (f16)hstate;
      }
      if (L1) ogp += pstep; else h0p += pstep;
      asm volatile("s_waitcnt lgkmcnt(0)" ::: "memory");
      __builtin_amdgcn_s_barrier();
    }
    xrA = xrB; xzA = xzB; xnA = xnB;
    if (L1) xfA = xfB;
  }
}

__global__ __launch_bounds__(256, 1) void gru_rec10_kernel(
    const f16* __restrict__ xgT, const f16* __restrict__ whhp,
    const float* __restrict__ bhh, const f16* __restrict__ xfT,
    f16* __restrict__ h0out, float* __restrict__ ogout)
{
  const int b = blockIdx.x >> 1, d = blockIdx.x & 1;
  const f16* xg_b = xgT + (size_t)(d * 64 + b) * 3 * 128 * 2048;
  const f16* xf_b = xfT ? (xfT + (size_t)(d * 64 + b) * 128 * 2048) : nullptr;
  const f16* whh_d = whhp + (size_t)d * 384 * 128;
  const float* bhh_d = bhh + d * 384;
  const int tid = threadIdx.x, wv = tid >> 6, lane = tid & 63;
  const int j = wv * 32 + (lane >> 1);
  f16* h0_b = h0out ? (h0out + (size_t)b * 524288 + d * 128 + j) : nullptr;
  float* og_b = ogout ? (ogout + (size_t)b * 524288 + d * 128 + j) : nullptr;

  if (ogout) {
    if (d == 0) gru_chain<0, 1>(xg_b, xf_b, whh_d, bhh_d, nullptr, og_b);
    else        gru_chain<1, 1>(xg_b, xf_b, whh_d, bhh_d, nullptr, og_b);
  } else {
    if (d == 0) gru_chain<0, 0>(xg_b, nullptr, whh_d, bhh_d, h0_b, nullptr);
    else        gru_chain<1, 0>(xg_b, nullptr, whh_d, bhh_d, h0_b, nullptr);
  }
}

// ---------- final head ----------
__global__ __launch_bounds__(256) void fc_out_kernel(
    const float* __restrict__ og, const float* __restrict__ fcw,
    const float* __restrict__ fcb, float* __restrict__ out)
{
  const int lane = threadIdx.x & 63;
  const int wid = (blockIdx.x * 256 + threadIdx.x) >> 6;
  const int nw = (gridDim.x * 256) >> 6;
  const f4_t w0 = *(const f4_t*)(fcw + 0 * 256 + lane * 4);
  const f4_t w1 = *(const f4_t*)(fcw + 1 * 256 + lane * 4);
  const f4_t w2 = *(const f4_t*)(fcw + 2 * 256 + lane * 4);
  const f4_t w3 = *(const f4_t*)(fcw + 3 * 256 + lane * 4);
  const float b0 = fcb[0], b1 = fcb[1], b2 = fcb[2], b3 = fcb[3];
  for (int row = wid; row < BT_; row += nw) {
    const f4_t v = *(const f4_t*)(og + (size_t)row * 256 + lane * 4);
    float p0 = v[0] * w0[0] + v[1] * w0[1] + v[2] * w0[2] + v[3] * w0[3];
    float p1 = v[0] * w1[0] + v[1] * w1[1] + v[2] * w1[2] + v[3] * w1[3];
    float p2 = v[0] * w2[0] + v[1] * w2[1] + v[2] * w2[2] + v[3] * w2[3];
    float p3 = v[0] * w3[0] + v[1] * w3[1] + v[2] * w3[2] + v[3] * w3[3];
#pragma unroll
    for (int off = 1; off < 64; off <<= 1) {
      p0 += __shfl_xor(p0, off);
      p1 += __shfl_xor(p1, off);
      p2 += __shfl_xor(p2, off);
      p3 += __shfl_xor(p3, off);
    }
    if (lane == 0) {
      f4_t o4 = f4_t{p0 + b0, p1 + b1, p2 + b2, p3 + b3};
      *(f4_t*)(out + (size_t)row * 4) = o4;
    }
  }
}

extern "C" void kernel_launch(void* const* d_in, const int* in_sizes, int n_in,
                              void* d_out, int out_size, void* d_ws, size_t ws_size,
                              hipStream_t stream)
{
  const float* x       = (const float*)d_in[0];
  const float* conv1_w = (const float*)d_in[1];
  const float* conv1_b = (const float*)d_in[2];
  const float* conv3_w = (const float*)d_in[3];
  const float* conv3_b = (const float*)d_in[4];
  const float* conv5_w = (const float*)d_in[5];
  const float* conv5_b = (const float*)d_in[6];
  const float* fc1_w   = (const float*)d_in[7];
  const float* fc1_b   = (const float*)d_in[8];
  const float* fc_w    = (const float*)d_in[9];
  const float* fc_b    = (const float*)d_in[10];
  const float* gru_wih = (const float*)d_in[11];
  const float* gru_whh = (const float*)d_in[12];
  const float* gru_bih = (const float*)d_in[13];
  const float* gru_bhh = (const float*)d_in[14];

  size_t off = 0;
  auto alloc = [&](size_t bytes) {
    char* p = (char*)d_ws + off;
    off += (bytes + 255) & ~(size_t)255;
    return p;
  };
  f16* A5   = (f16*)alloc((size_t)BT_ * 480 * 2);
  f16* W5p  = (f16*)alloc(256 * 480 * 2);
  f16* W3p  = (f16*)alloc(256 * 288 * 2);
  f16* W1p  = (f16*)alloc(256 * 96 * 2);
  f16* FC1p = (f16*)alloc(256 * 96 * 2);
  f16* wihp = (f16*)alloc(4ull * 384 * 256 * 2);
  f16* whhp = (f16*)alloc(4ull * 384 * 128 * 2);
  f16* oc   = (f16*)alloc((size_t)BT_ * 256 * 2);
  f16* xgT  = (f16*)alloc(2ull * 64 * 3 * 128 * 2048 * 2);
  f16* h0   = (f16*)alloc((size_t)BT_ * 256 * 2);
  f16* xfT  = (f16*)alloc(2ull * 64 * 128 * 2048 * 2);
  if (off > ws_size) return;

  float* og   = (float*)d_out;
  float* out2 = (float*)d_out + OG_ELEMS;

  im2col_kernel<<<dim3(BT_ / 32, 5), 384, 0, stream>>>(x, A5);
  pack_convw_kernel<<<960, 256, 0, stream>>>(conv1_w, conv3_w, conv5_w, fc1_w,
                                             W5p, W3p, W1p, FC1p);
  cast_f16_kernel<<<(49152 + 255) / 256, 256, 0, stream>>>(gru_wih, wihp, 49152);
  cast_f16_kernel<<<(24576 + 255) / 256, 256, 0, stream>>>(gru_whh, whhp, 24576);

  conv3sum_kernel<<<dim3(1024, 2), 256, 0, stream>>>(A5, W5p, W3p, W1p,
                                                     conv5_b, conv3_b, conv1_b, oc);
  // fc1 residual path -> transposed chain layout
  gemm_xT_kernel<<<dim3(1024, 2), 256, 0, stream>>>(A5 + 192, 480, FC1p, 96,
                                                    fc1_b, xfT, 3, 1);

  for (int l = 0; l < 2; ++l) {
    const f16* hin = l ? h0 : oc;
    for (int d = 0; d < 2; ++d) {
      gemm_xT_kernel<<<dim3(1024, 3), 256, 0, stream>>>(
          hin, 256, wihp + (size_t)(l * 2 + d) * 384 * 256, 256,
          gru_bih + (l * 2 + d) * 384,
          xgT + (size_t)d * 64 * 3 * 128 * 2048, 8, 0);
    }
    gru_rec10_kernel<<<128, 256, 0, stream>>>(
        xgT, whhp + (size_t)l * 2 * 384 * 128, gru_bhh + (size_t)l * 2 * 384,
        l ? xfT : nullptr, l ? nullptr : h0, l ? og : nullptr);
  }

  fc_out_kernel<<<1024, 256, 0, stream>>>(og, fc_w, fc_b, out2);
}

// Round 11
// 2171.439 us; speedup vs baseline: 3.7231x; 1.0203x over previous
//
#include <hip/hip_runtime.h>
#include <hip/hip_bf16.h>
#include <hip/hip_fp16.h>

typedef _Float16 f16;
typedef _Float16 h2_t __attribute__((ext_vector_type(2)));
typedef _Float16 h4_t __attribute__((ext_vector_type(4)));
typedef _Float16 h8_t __attribute__((ext_vector_type(8)));
typedef float    f4_t __attribute__((ext_vector_type(4)));

#define B_  64
#define T_  2048
#define BT_ 131072   // B_*T_
#define OG_ELEMS 33554432ull  // BT_*256

// ---------- async global->LDS (16B per lane, wave-uniform LDS base) ----------
__device__ __forceinline__ void gl_lds16(const void* g, void* lds) {
  __builtin_amdgcn_global_load_lds(
      (const __attribute__((address_space(1))) void*)g,
      (__attribute__((address_space(3))) void*)lds, 16, 0, 0);
}

__device__ __forceinline__ float fastrcp(float x)  { return __builtin_amdgcn_rcpf(x); }
__device__ __forceinline__ float fastex2(float x)  { return __builtin_amdgcn_exp2f(x); }

// register-only pair swap (lane ^ 1) via DPP quad_perm [1,0,3,2]
__device__ __forceinline__ float dpp_swap1(float x) {
  int i = __builtin_bit_cast(int, x);
  int y = __builtin_amdgcn_update_dpp(0, i, 0xB1, 0xF, 0xF, true);
  return __builtin_bit_cast(float, y);
}

// ---------- m97-style K-loop: 128x128 tile, BK=32, f16 MFMA ----------
__device__ __forceinline__ void kloop128(
    const f16* __restrict__ Ab, int lda,
    const f16* __restrict__ Bb, int ldb,
    int ksteps, f16* As, f16* Bs, f4_t (&acc)[4][4])
{
  const int tid  = threadIdx.x;
  const int wave = tid >> 6, lane = tid & 63;
  const int srow = tid >> 2;
  const int scol = (tid & 3) * 8;
  const int fr   = lane & 15;
  const int kb   = (lane >> 4) * 8;
  const int rA   = (wave >> 1) * 64 + fr;
  const int rB   = (wave & 1) * 64 + fr;

  f16* dA0 = As + wave * 512;
  f16* dA1 = As + 2048 + wave * 512;
  f16* dB0 = Bs + wave * 512;
  f16* dB1 = Bs + 2048 + wave * 512;
  const f16* gA0 = Ab + (size_t)srow * lda + scol;
  const f16* gA1 = Ab + (size_t)(srow + 64) * lda + scol;
  const f16* gB0 = Bb + (size_t)srow * ldb + scol;
  const f16* gB1 = Bb + (size_t)(srow + 64) * ldb + scol;

  for (int kt = 0; kt < ksteps; ++kt) {
    const int ko = kt * 32;
    gl_lds16(gA0 + ko, dA0);
    gl_lds16(gA1 + ko, dA1);
    gl_lds16(gB0 + ko, dB0);
    gl_lds16(gB1 + ko, dB1);
    __syncthreads();
    h8_t af[4], bf[4];
#pragma unroll
    for (int m = 0; m < 4; m++) af[m] = *(const h8_t*)(As + (rA + m * 16) * 32 + kb);
#pragma unroll
    for (int n = 0; n < 4; n++) bf[n] = *(const h8_t*)(Bs + (rB + n * 16) * 32 + kb);
#pragma unroll
    for (int m = 0; m < 4; m++)
#pragma unroll
      for (int n = 0; n < 4; n++)
        acc[m][n] = __builtin_amdgcn_mfma_f32_16x16x32_f16(af[m], bf[n], acc[m][n], 0, 0, 0);
    __syncthreads();
  }
}

// ---------- GEMM with transposed per-chain store ----------
// mode 0 (xg): out[((b*3 + g)*128 + j)*2048 + t],  d = blockIdx.z selects weights
// mode 1 (xf): out[((g*64 + b)*128 + j)*2048 + t]
__global__ __launch_bounds__(256) void gemm_xT_kernel(
    const f16* __restrict__ A, int lda,
    const f16* __restrict__ Bw, int ldb, size_t bw_dstride,
    const float* __restrict__ bias, int bias_dstride,
    f16* __restrict__ out, size_t out_dstride, int ksteps, int mode)
{
  __shared__ f16 As[4096];
  __shared__ f16 Bs[4096];
  f4_t acc[4][4];
#pragma unroll
  for (int m = 0; m < 4; m++)
#pragma unroll
    for (int n = 0; n < 4; n++) acc[m][n] = f4_t{0.f, 0.f, 0.f, 0.f};

  const int dz = blockIdx.z;
  const f16* Ab = A + (size_t)blockIdx.x * 128 * lda;
  const f16* Bb = Bw + dz * bw_dstride + (size_t)blockIdx.y * 128 * ldb;
  kloop128(Ab, lda, Bb, ldb, ksteps, As, Bs, acc);

  const int tid = threadIdx.x, wave = tid >> 6, lane = tid & 63;
  const int col0 = blockIdx.y * 128 + (wave & 1) * 64 + (lane & 15);
  const int row0 = blockIdx.x * 128 + (wave >> 1) * 64 + (lane >> 4) * 4;
  const int b = blockIdx.x >> 4;   // 16 row-blocks per batch (2048/128)
  const float* biasd = bias + dz * bias_dstride;
  f16* outd = out + dz * out_dstride;
#pragma unroll
  for (int n = 0; n < 4; n++) {
    const int col = col0 + n * 16;
    const float bv = biasd[col];
    const int g = col >> 7, jj = col & 127;
    const size_t base = (mode == 0)
        ? ((size_t)((b * 3 + g) * 128 + jj)) * 2048
        : ((size_t)((g * 64 + b) * 128 + jj)) * 2048;
#pragma unroll
    for (int m = 0; m < 4; m++) {
      const int row = row0 + m * 16;
      const int t = row & 2047;
      h4_t v = h4_t{(f16)(acc[m][n][0] + bv), (f16)(acc[m][n][1] + bv),
                    (f16)(acc[m][n][2] + bv), (f16)(acc[m][n][3] + bv)};
      *(h4_t*)(outd + base + t) = v;
    }
  }
}

// ---------- conv: sum of 3 relu'd GEMM segments (row-major out) ----------
__global__ __launch_bounds__(256) void conv3sum_kernel(
    const f16* __restrict__ A5,
    const f16* __restrict__ W5p, const f16* __restrict__ W3p, const f16* __restrict__ W1p,
    const float* __restrict__ b5, const float* __restrict__ b3, const float* __restrict__ b1,
    f16* __restrict__ oc)
{
  __shared__ f16 As[4096];
  __shared__ f16 Bs[4096];
  const int tid = threadIdx.x, wave = tid >> 6, lane = tid & 63;
  const int col0 = blockIdx.y * 128 + (wave & 1) * 64 + (lane & 15);
  const int row0 = blockIdx.x * 128 + (wave >> 1) * 64 + (lane >> 4) * 4;
  const f16* Ab = A5 + (size_t)blockIdx.x * 128 * 480;

  f4_t tot[4][4];
#pragma unroll
  for (int m = 0; m < 4; m++)
#pragma unroll
    for (int n = 0; n < 4; n++) tot[m][n] = f4_t{0.f, 0.f, 0.f, 0.f};

  auto seg = [&](const f16* Wp, int ldb, int ks, int aoff, const float* bias) {
    f4_t acc[4][4];
#pragma unroll
    for (int m = 0; m < 4; m++)
#pragma unroll
      for (int n = 0; n < 4; n++) acc[m][n] = f4_t{0.f, 0.f, 0.f, 0.f};
    kloop128(Ab + aoff, 480, Wp + (size_t)blockIdx.y * 128 * ldb, ldb, ks, As, Bs, acc);
#pragma unroll
    for (int n = 0; n < 4; n++) {
      const float bv = bias[col0 + n * 16];
#pragma unroll
      for (int m = 0; m < 4; m++)
#pragma unroll
        for (int q = 0; q < 4; q++)
          tot[m][n][q] += fmaxf(acc[m][n][q] + bv, 0.f);
    }
  };
  seg(W5p, 480, 15, 0,   b5);
  seg(W3p, 288, 9,  96,  b3);
  seg(W1p, 96,  3,  192, b1);

#pragma unroll
  for (int n = 0; n < 4; n++) {
    const int col = col0 + n * 16;
#pragma unroll
    for (int m = 0; m < 4; m++) {
      const int row = row0 + m * 16;
#pragma unroll
      for (int q = 0; q < 4; q++)
        oc[(size_t)(row + q) * 256 + col] = (f16)tot[m][n][q];
    }
  }
}

// ---------- im2col ----------
__global__ __launch_bounds__(384) void im2col_kernel(
    const float* __restrict__ x, f16* __restrict__ A5)
{
  const int tid = threadIdx.x;
  const int r = tid / 12, c8 = tid % 12;
  const int bt = blockIdx.x * 32 + r;
  const int kg = blockIdx.y;
  const int b = bt >> 11, t = bt & 2047;
  const int ts = t + kg - 2;
  h8_t v = {0, 0, 0, 0, 0, 0, 0, 0};
  if (c8 < 10 && (unsigned)ts < 2048u) {
    const float* src = x + ((size_t)(b << 11) + ts) * 80 + c8 * 8;
    f4_t a = *(const f4_t*)src;
    f4_t bvec = *(const f4_t*)(src + 4);
    v = h8_t{(f16)a[0], (f16)a[1], (f16)a[2], (f16)a[3],
             (f16)bvec[0], (f16)bvec[1], (f16)bvec[2], (f16)bvec[3]};
  }
  *(h8_t*)(A5 + (size_t)bt * 480 + kg * 96 + c8 * 8) = v;
}

// ---------- weight packing ----------
__global__ void pack_convw_kernel(
    const float* __restrict__ w1, const float* __restrict__ w3,
    const float* __restrict__ w5, const float* __restrict__ fc1w,
    f16* __restrict__ W5p, f16* __restrict__ W3p, f16* __restrict__ W1p,
    f16* __restrict__ FC1p)
{
  const int col = blockIdx.x;
  const int c = threadIdx.x;
  if (col < 480) {
    const int kg = col / 96, d = col % 96;
    W5p[c * 480 + col] = (f16)((d < 80) ? w5[(c * 80 + d) * 5 + kg] : 0.f);
  } else if (col < 768) {
    const int cc = col - 480, k = cc / 96, d = cc % 96;
    W3p[c * 288 + cc] = (f16)((d < 80) ? w3[(c * 80 + d) * 3 + k] : 0.f);
  } else if (col < 864) {
    const int d = col - 768;
    W1p[c * 96 + d] = (f16)((d < 80) ? w1[c * 80 + d] : 0.f);
  } else {
    const int d = col - 864;
    FC1p[c * 96 + d] = (f16)((d < 80) ? fc1w[c * 80 + d] : 0.f);
  }
}

__global__ void cast_f16_kernel(const float* __restrict__ src, f16* __restrict__ dst, int n8)
{
  const int i = blockIdx.x * blockDim.x + threadIdx.x;
  if (i >= n8) return;
  f4_t a = *(const f4_t*)(src + (size_t)i * 8);
  f4_t b = *(const f4_t*)(src + (size_t)i * 8 + 4);
  h8_t v = h8_t{(f16)a[0], (f16)a[1], (f16)a[2], (f16)a[3],
                (f16)b[0], (f16)b[1], (f16)b[2], (f16)b[3]};
  *(h8_t*)(dst + (size_t)i * 8) = v;
}

// ---------- GRU recurrence v7 (best measured): pair-split K, f16 weights,
// ---------- DPP pair-reduce, fast gates, one barrier/step ----------
#define DOT8(acc0, acc1, hv, wv)                                                       \
  do {                                                                                 \
    acc0 = __builtin_amdgcn_fdot2(h2_t{hv[0], hv[1]}, h2_t{wv[0], wv[1]}, acc0, false);\
    acc1 = __builtin_amdgcn_fdot2(h2_t{hv[2], hv[3]}, h2_t{wv[2], wv[3]}, acc1, false);\
    acc0 = __builtin_amdgcn_fdot2(h2_t{hv[4], hv[5]}, h2_t{wv[4], wv[5]}, acc0, false);\
    acc1 = __builtin_amdgcn_fdot2(h2_t{hv[6], hv[7]}, h2_t{wv[6], wv[7]}, acc1, false);\
  } while (0)

template<int DIR, int L1>
__device__ __forceinline__ void gru_chain(
    const f16* __restrict__ xg_b,   // + (d*64+b)*3*128*2048
    const f16* __restrict__ xf_b,   // + (d*64+b)*128*2048   (L1 only)
    const f16* __restrict__ whh_d,  // packed f16, this dir (384*128)
    const float* __restrict__ bhh_d,
    f16* __restrict__ h0_b,         // + b*2048*256 + d*128  (L0)
    float* __restrict__ og_b)       // same offset            (L1)
{
  const int tid  = threadIdx.x;      // 256
  const int wv   = tid >> 6;
  const int lane = tid & 63;
  const int j    = wv * 32 + (lane >> 1);   // 0..127 output unit
  const int kh   = lane & 1;                // K-half owner
  const int co   = kh * 64;

  // weights: rows j (r), 128+j (z), 256+j (n); cols [kh*64, kh*64+64)
  h8_t WR[8], WZ[8], WN[8];
#pragma unroll
  for (int q = 0; q < 8; q++) WR[q] = *(const h8_t*)(whh_d + (size_t)j * 128 + co + q * 8);
#pragma unroll
  for (int q = 0; q < 8; q++) WZ[q] = *(const h8_t*)(whh_d + (size_t)(128 + j) * 128 + co + q * 8);
#pragma unroll
  for (int q = 0; q < 8; q++) WN[q] = *(const h8_t*)(whh_d + (size_t)(256 + j) * 128 + co + q * 8);
  const float br = bhh_d[j], bz = bhh_d[128 + j], bn = bhh_d[256 + j];

  __shared__ __align__(16) f16 hb[2][128];
  if (tid < 128) { hb[0][tid] = (f16)0.f; hb[1][tid] = (f16)0.f; }
  float hstate = 0.f;

  h8_t xrA{}, xzA{}, xnA{}, xfA{};
  h8_t xrB{}, xzB{}, xnB{}, xfB{};
  auto ld4 = [&](int s8, h8_t& xr, h8_t& xz, h8_t& xn, h8_t& xf) {
    const int tb = DIR ? (T_ - 8 - s8) : s8;
    xr = *(const h8_t*)(xg_b + (size_t)(0 * 128 + j) * 2048 + tb);
    xz = *(const h8_t*)(xg_b + (size_t)(1 * 128 + j) * 2048 + tb);
    xn = *(const h8_t*)(xg_b + (size_t)(2 * 128 + j) * 2048 + tb);
    if (L1) xf = *(const h8_t*)(xf_b + (size_t)j * 2048 + tb);
  };
  ld4(0, xrA, xzA, xnA, xfA);
  asm volatile("s_waitcnt lgkmcnt(0)" ::: "memory");
  __builtin_amdgcn_s_barrier();
  __builtin_amdgcn_sched_barrier(0);

  for (int s8 = 0; s8 < T_; s8 += 8) {
    if ((s8 + 8) < T_) ld4(s8 + 8, xrB, xzB, xnB, xfB);
#pragma unroll
    for (int ss = 0; ss < 8; ss++) {
      const int e = DIR ? (7 - ss) : ss;
      // --- read h K-half from current buffer ---
      const f16* hbuf = &hb[ss & 1][0] + co;
      h8_t hv[8];
#pragma unroll
      for (int q = 0; q < 8; q++) hv[q] = *(const h8_t*)(hbuf + q * 8);
      // --- 3-gate half-dots, 6 accumulator chains ---
      float r0 = 0.f, r1 = 0.f, z0 = 0.f, z1 = 0.f, n0 = 0.f, n1 = 0.f;
#pragma unroll
      for (int q = 0; q < 8; q++) {
        DOT8(r0, r1, hv[q], WR[q]);
        DOT8(z0, z1, hv[q], WZ[q]);
        DOT8(n0, n1, hv[q], WN[q]);
      }
      // register-only pair reduce (lane^1) via DPP
      float sr = r0 + r1; sr += dpp_swap1(sr);
      float sz = z0 + z1; sz += dpp_swap1(sz);
      float sn = n0 + n1; sn += dpp_swap1(sn);
      // --- gates (redundant on both pair lanes; no divergence) ---
      const float rr = fastrcp(1.f + fastex2(((float)xrA[e] + sr + br) * -1.44269504f));
      const float zz = fastrcp(1.f + fastex2(((float)xzA[e] + sz + bz) * -1.44269504f));
      const float na = (float)xnA[e] + rr * (sn + bn);
      const float ex = fastex2(fabsf(na) * 2.88539008f);
      const float th = copysignf(1.f - 2.f * fastrcp(ex + 1.f), na);
      hstate = (1.f - zz) * th + zz * hstate;
      const int t = DIR ? (T_ - 1 - (s8 + ss)) : (s8 + ss);
      if (!kh) {
        if (L1) og_b[(size_t)t * 256 + j] = hstate + (float)xfA[e];
        else    h0_b[(size_t)t * 256 + j] = (f16)hstate;
        hb[(ss & 1) ^ 1][j] = (f16)hstate;
      }
      asm volatile("s_waitcnt lgkmcnt(0)" ::: "memory");
      __builtin_amdgcn_s_barrier();
      __builtin_amdgcn_sched_barrier(0);
    }
    xrA = xrB; xzA = xzB; xnA = xnB;
    if (L1) xfA = xfB;
  }
}

__global__ __launch_bounds__(256, 1) void gru_rec7_kernel(
    const f16* __restrict__ xgT, const f16* __restrict__ whhp,
    const float* __restrict__ bhh, const f16* __restrict__ xfT,
    f16* __restrict__ h0out, float* __restrict__ ogout)
{
  const int b = blockIdx.x >> 1, d = blockIdx.x & 1;
  const f16* xg_b = xgT + (size_t)(d * 64 + b) * 3 * 128 * 2048;
  const f16* xf_b = xfT ? (xfT + (size_t)(d * 64 + b) * 128 * 2048) : nullptr;
  const f16* whh_d = whhp + (size_t)d * 384 * 128;
  const float* bhh_d = bhh + d * 384;
  f16* h0_b = h0out ? (h0out + (size_t)b * 2048 * 256 + d * 128) : nullptr;
  float* og_b = ogout ? (ogout + (size_t)b * 2048 * 256 + d * 128) : nullptr;

  if (ogout) {
    if (d == 0) gru_chain<0, 1>(xg_b, xf_b, whh_d, bhh_d, nullptr, og_b);
    else        gru_chain<1, 1>(xg_b, xf_b, whh_d, bhh_d, nullptr, og_b);
  } else {
    if (d == 0) gru_chain<0, 0>(xg_b, nullptr, whh_d, bhh_d, h0_b, nullptr);
    else        gru_chain<1, 0>(xg_b, nullptr, whh_d, bhh_d, h0_b, nullptr);
  }
}

// ---------- final head ----------
__global__ __launch_bounds__(256) void fc_out_kernel(
    const float* __restrict__ og, const float* __restrict__ fcw,
    const float* __restrict__ fcb, float* __restrict__ out)
{
  const int lane = threadIdx.x & 63;
  const int wid = (blockIdx.x * 256 + threadIdx.x) >> 6;
  const int nw = (gridDim.x * 256) >> 6;
  const f4_t w0 = *(const f4_t*)(fcw + 0 * 256 + lane * 4);
  const f4_t w1 = *(const f4_t*)(fcw + 1 * 256 + lane * 4);
  const f4_t w2 = *(const f4_t*)(fcw + 2 * 256 + lane * 4);
  const f4_t w3 = *(const f4_t*)(fcw + 3 * 256 + lane * 4);
  const float b0 = fcb[0], b1 = fcb[1], b2 = fcb[2], b3 = fcb[3];
  for (int row = wid; row < BT_; row += nw) {
    const f4_t v = *(const f4_t*)(og + (size_t)row * 256 + lane * 4);
    float p0 = v[0] * w0[0] + v[1] * w0[1] + v[2] * w0[2] + v[3] * w0[3];
    float p1 = v[0] * w1[0] + v[1] * w1[1] + v[2] * w1[2] + v[3] * w1[3];
    float p2 = v[0] * w2[0] + v[1] * w2[1] + v[2] * w2[2] + v[3] * w2[3];
    float p3 = v[0] * w3[0] + v[1] * w3[1] + v[2] * w3[2] + v[3] * w3[3];
#pragma unroll
    for (int off = 1; off < 64; off <<= 1) {
      p0 += __shfl_xor(p0, off);
      p1 += __shfl_xor(p1, off);
      p2 += __shfl_xor(p2, off);
      p3 += __shfl_xor(p3, off);
    }
    if (lane == 0) {
      f4_t o4 = f4_t{p0 + b0, p1 + b1, p2 + b2, p3 + b3};
      *(f4_t*)(out + (size_t)row * 4) = o4;
    }
  }
}

extern "C" void kernel_launch(void* const* d_in, const int* in_sizes, int n_in,
                              void* d_out, int out_size, void* d_ws, size_t ws_size,
                              hipStream_t stream)
{
  const float* x       = (const float*)d_in[0];
  const float* conv1_w = (const float*)d_in[1];
  const float* conv1_b = (const float*)d_in[2];
  const float* conv3_w = (const float*)d_in[3];
  const float* conv3_b = (const float*)d_in[4];
  const float* conv5_w = (const float*)d_in[5];
  const float* conv5_b = (const float*)d_in[6];
  const float* fc1_w   = (const float*)d_in[7];
  const float* fc1_b   = (const float*)d_in[8];
  const float* fc_w    = (const float*)d_in[9];
  const float* fc_b    = (const float*)d_in[10];
  const float* gru_wih = (const float*)d_in[11];
  const float* gru_whh = (const float*)d_in[12];
  const float* gru_bih = (const float*)d_in[13];
  const float* gru_bhh = (const float*)d_in[14];

  size_t off = 0;
  auto alloc = [&](size_t bytes) {
    char* p = (char*)d_ws + off;
    off += (bytes + 255) & ~(size_t)255;
    return p;
  };
  f16* A5   = (f16*)alloc((size_t)BT_ * 480 * 2);
  f16* W5p  = (f16*)alloc(256 * 480 * 2);
  f16* W3p  = (f16*)alloc(256 * 288 * 2);
  f16* W1p  = (f16*)alloc(256 * 96 * 2);
  f16* FC1p = (f16*)alloc(256 * 96 * 2);
  f16* wihp = (f16*)alloc(4ull * 384 * 256 * 2);
  f16* whhp = (f16*)alloc(4ull * 384 * 128 * 2);
  f16* oc   = (f16*)alloc((size_t)BT_ * 256 * 2);
  f16* xgT  = (f16*)alloc(2ull * 64 * 3 * 128 * 2048 * 2);
  f16* h0   = (f16*)alloc((size_t)BT_ * 256 * 2);
  f16* xfT  = (f16*)alloc(2ull * 64 * 128 * 2048 * 2);
  if (off > ws_size) return;

  float* og   = (float*)d_out;
  float* out2 = (float*)d_out + OG_ELEMS;

  im2col_kernel<<<dim3(BT_ / 32, 5), 384, 0, stream>>>(x, A5);
  pack_convw_kernel<<<960, 256, 0, stream>>>(conv1_w, conv3_w, conv5_w, fc1_w,
                                             W5p, W3p, W1p, FC1p);
  cast_f16_kernel<<<(49152 + 255) / 256, 256, 0, stream>>>(gru_wih, wihp, 49152);
  cast_f16_kernel<<<(24576 + 255) / 256, 256, 0, stream>>>(gru_whh, whhp, 24576);

  conv3sum_kernel<<<dim3(1024, 2), 256, 0, stream>>>(A5, W5p, W3p, W1p,
                                                     conv5_b, conv3_b, conv1_b, oc);
  // fc1 residual path -> transposed chain layout (z=1, strides 0)
  gemm_xT_kernel<<<dim3(1024, 2, 1), 256, 0, stream>>>(
      A5 + 192, 480, FC1p, 96, 0, fc1_b, 0, xfT, 0, 3, 1);

  for (int l = 0; l < 2; ++l) {
    const f16* hin = l ? h0 : oc;
    // both directions in ONE dispatch: z = d
    gemm_xT_kernel<<<dim3(1024, 3, 2), 256, 0, stream>>>(
        hin, 256,
        wihp + (size_t)(l * 2) * 384 * 256, 256, (size_t)384 * 256,
        gru_bih + (l * 2) * 384, 384,
        xgT, (size_t)64 * 3 * 128 * 2048, 8, 0);
    gru_rec7_kernel<<<128, 256, 0, stream>>>(
        xgT, whhp + (size_t)l * 2 * 384 * 128, gru_bhh + (size_t)l * 2 * 384,
        l ? xfT : nullptr, l ? nullptr : h0, l ? og : nullptr);
  }

  fc_out_kernel<<<1024, 256, 0, stream>>>(og, fc_w, fc_b, out2);
}